// Round 6
// baseline (181.595 us; speedup 1.0000x reference)
//
#include <hip/hip_runtime.h>
#include <math.h>

#define NU 20000
#define NI 20000
#define NT 5000
#define NN 45000
#define D  64
#define CAP 64

typedef unsigned short u16;
typedef unsigned int u32;

typedef __attribute__((ext_vector_type(8))) short bf16x8;
typedef __attribute__((ext_vector_type(4))) float f32x4;

__device__ __forceinline__ float b2f(u16 u) {
  return __uint_as_float(((u32)u) << 16);
}
__device__ __forceinline__ u16 f2b(float f) {
  u32 x = __float_as_uint(f);
  u32 r = (x + 0x7fffu + ((x >> 16) & 1u)) >> 16;
  return (u16)r;
}
__device__ __forceinline__ const float* row3(int n, const float* a, const float* b, const float* c) {
  if (n < NU) return a + (size_t)n * D;
  if (n < NU + NI) return b + (size_t)(n - NU) * D;
  return c + (size_t)(n - NU - NI) * D;
}
__device__ __forceinline__ bf16x8 cvtf8(const float* p) {
  bf16x8 r;
#pragma unroll
  for (int j = 0; j < 8; ++j) r[j] = (short)f2b(p[j]);
  return r;
}

// ---------------- prep: pack offsets + convert W + capacity-CSR scatter ----------------
#define PACKB 11250   // NN*64/256
#define WB 32         // 8192/256
__global__ __launch_bounds__(256) void prep_kernel(
    const float* __restrict__ uo, const float* __restrict__ io, const float* __restrict__ to,
    const float* __restrict__ W1, const float* __restrict__ W2,
    u16* __restrict__ O1, u16* __restrict__ W1b, u16* __restrict__ W2b,
    int* __restrict__ cnt, u16* __restrict__ csr_tail,
    const int* __restrict__ head, const int* __restrict__ tail, int E) {
  int bid = blockIdx.x;
  if (bid < PACKB) {
    int i = bid * 256 + threadIdx.x;   // < NN*64 exactly
    int n = i >> 6, c = i & 63;
    const float* op;
    if (n < NU)           op = uo + (size_t)n * D;
    else if (n < NU + NI) op = io + (size_t)(n - NU) * D;
    else                  op = to + (size_t)(n - NU - NI) * D;
    O1[i] = f2b(fmaxf(op[c], 0.f));
  } else if (bid < PACKB + WB) {
    int i = (bid - PACKB) * 256 + threadIdx.x;
    if (i < 4096) W1b[i] = f2b(W1[i]);
    else          W2b[i - 4096] = f2b(W2[i - 4096]);
  } else {
    int i = (bid - PACKB - WB) * 256 + threadIdx.x;
    if (i < E) {
      int h = head[i];
      int s = atomicAdd(&cnt[h], 1);
      if (s < CAP) __builtin_nontemporal_store((u16)tail[i], &csr_tail[h * CAP + s]);
    }
  }
}

// ---------------- MFMA node MLP: PE = [p=exp(clamp(mlp(x))) | e] ----------------
// FIRST=1: x,e from raw f32 inputs; FIRST=0: x,e from bf16 Xc.
template <int FIRST>
__global__ __launch_bounds__(256) void mlp_kernel(
    const float* __restrict__ ue, const float* __restrict__ ie, const float* __restrict__ te,
    const u16* __restrict__ Xc,
    const u16* __restrict__ W1b, const u16* __restrict__ W2b,
    const float* __restrict__ b1, const float* __restrict__ b2,
    u32* __restrict__ PE) {
  __shared__ u16 Hs[64][72];
  int tid = threadIdx.x;
  int w = tid >> 6, l = tid & 63;
  int lr = l & 15, kh = l >> 4;
  int nbase = blockIdx.x * 64 + w * 16;
  int na = nbase + lr; if (na > NN - 1) na = NN - 1;
  bf16x8 A0, A1;
  if (FIRST) {
    const float* xr = row3(na, ue, ie, te);
    A0 = cvtf8(xr + kh * 8);
    A1 = cvtf8(xr + 32 + kh * 8);
  } else {
    A0 = *(const bf16x8*)(Xc + (size_t)na * 64 + kh * 8);
    A1 = *(const bf16x8*)(Xc + (size_t)na * 64 + 32 + kh * 8);
  }
#pragma unroll
  for (int ft = 0; ft < 4; ++ft) {
    int f = ft * 16 + lr;
    bf16x8 Bl = *(const bf16x8*)(W1b + (size_t)f * 64 + kh * 8);
    bf16x8 Bh = *(const bf16x8*)(W1b + (size_t)f * 64 + 32 + kh * 8);
    f32x4 z = {0.f, 0.f, 0.f, 0.f};
    z = __builtin_amdgcn_mfma_f32_16x16x32_bf16(A0, Bl, z, 0, 0, 0);
    z = __builtin_amdgcn_mfma_f32_16x16x32_bf16(A1, Bh, z, 0, 0, 0);
    float bb = b1[f];
#pragma unroll
    for (int r = 0; r < 4; ++r)
      Hs[w * 16 + kh * 4 + r][f] = f2b(fmaxf(z[r] + bb, 0.f));
  }
  __syncthreads();
  bf16x8 A20 = *(const bf16x8*)&Hs[w * 16 + lr][kh * 8];
  bf16x8 A21 = *(const bf16x8*)&Hs[w * 16 + lr][32 + kh * 8];
#pragma unroll
  for (int ft = 0; ft < 4; ++ft) {
    int f = ft * 16 + lr;
    bf16x8 Bl = *(const bf16x8*)(W2b + (size_t)f * 64 + kh * 8);
    bf16x8 Bh = *(const bf16x8*)(W2b + (size_t)f * 64 + 32 + kh * 8);
    f32x4 z = {0.f, 0.f, 0.f, 0.f};
    z = __builtin_amdgcn_mfma_f32_16x16x32_bf16(A20, Bl, z, 0, 0, 0);
    z = __builtin_amdgcn_mfma_f32_16x16x32_bf16(A21, Bh, z, 0, 0, 0);
    float bb = b2[f];
#pragma unroll
    for (int r = 0; r < 4; ++r) {
      int node = nbase + kh * 4 + r;
      if (node < NN) {
        float a = z[r] + bb;
        float p = __expf(fminf(fmaxf(a, -60.f), 60.f));
        u32 eb;
        if (FIRST) eb = f2b(row3(node, ue, ie, te)[f]);
        else       eb = Xc[(size_t)node * 64 + f];
        PE[(size_t)node * 64 + f] = ((u32)f2b(p)) | (eb << 16);
      }
    }
  }
}

// ---------------- aggregation: two waves per node (role 0: softmax, role 1: offsets) ----------------
template <int FINAL>
__global__ __launch_bounds__(256) void agg_kernel(
    const int* __restrict__ cnt, const u16* __restrict__ csr_tail,
    const u32* __restrict__ PE, const u16* __restrict__ O,
    u16* __restrict__ Oo, u16* __restrict__ Xco,
    float* __restrict__ out) {
  int wid = (blockIdx.x * blockDim.x + threadIdx.x) >> 6;
  int lane = threadIdx.x & 63;
  int n = wid >> 1;
  if (n >= NN) return;
  int role = wid & 1;
  int cn = min(cnt[n], CAP);
  int tl = (lane < cn) ? (int)csr_tail[n * CAP + lane] : 0;

  if (role == 0) {
    float ss0 = 0.f, ss1 = 0.f, ss2 = 0.f, ss3 = 0.f;
    float ts0 = 0.f, ts1 = 0.f, ts2 = 0.f, ts3 = 0.f;
#define PEDGE(V, SS, TS)                          \
    {                                             \
      float p_ = b2f((u16)((V) & 0xffffu));       \
      float e_ = b2f((u16)((V) >> 16));           \
      SS += p_;                                   \
      TS = fmaf(p_, e_, TS);                      \
    }
    int j = 0;
    for (; j + 7 < cn; j += 8) {
      int t0 = __shfl(tl, j),     t1 = __shfl(tl, j + 1);
      int t2 = __shfl(tl, j + 2), t3 = __shfl(tl, j + 3);
      int t4 = __shfl(tl, j + 4), t5 = __shfl(tl, j + 5);
      int t6 = __shfl(tl, j + 6), t7 = __shfl(tl, j + 7);
      u32 v0 = PE[((u32)t0 << 6) + lane], v1 = PE[((u32)t1 << 6) + lane];
      u32 v2 = PE[((u32)t2 << 6) + lane], v3 = PE[((u32)t3 << 6) + lane];
      u32 v4 = PE[((u32)t4 << 6) + lane], v5 = PE[((u32)t5 << 6) + lane];
      u32 v6 = PE[((u32)t6 << 6) + lane], v7 = PE[((u32)t7 << 6) + lane];
      PEDGE(v0, ss0, ts0) PEDGE(v1, ss1, ts1) PEDGE(v2, ss2, ts2) PEDGE(v3, ss3, ts3)
      PEDGE(v4, ss0, ts0) PEDGE(v5, ss1, ts1) PEDGE(v6, ss2, ts2) PEDGE(v7, ss3, ts3)
    }
    for (; j < cn; ++j) {
      int t = __shfl(tl, j);
      u32 v = PE[((u32)t << 6) + lane];
      PEDGE(v, ss0, ts0)
    }
#undef PEDGE
    float ssum = (ss0 + ss1) + (ss2 + ss3);
    float tsum = (ts0 + ts1) + (ts2 + ts3);
    float agg = tsum / ssum;
    float sq = agg * agg;
#pragma unroll
    for (int msk = 1; msk < 64; msk <<= 1) sq += __shfl_xor(sq, msk);
    float outv = agg / fmaxf(sqrtf(sq), 1e-12f);
    if (FINAL) {
      float* oe;
      if (n < NU)           oe = out + (size_t)n * D;
      else if (n < NU + NI) oe = out + (size_t)2 * NU * D + (size_t)(n - NU) * D;
      else                  oe = out + (size_t)(2 * NU + 2 * NI) * D + (size_t)(n - NU - NI) * D;
      __builtin_nontemporal_store(outv, &oe[lane]);
    } else {
      Xco[((u32)n << 6) + lane] = f2b(outv);
    }
  } else {
    float offv;
    if (n < NU) {
      float omin = 3.4e38f, omax = -3.4e38f;
      int j = 0;
      for (; j + 3 < cn; j += 4) {
        int t0 = __shfl(tl, j),     t1 = __shfl(tl, j + 1);
        int t2 = __shfl(tl, j + 2), t3 = __shfl(tl, j + 3);
        float o0 = b2f(O[((u32)t0 << 6) + lane]), o1 = b2f(O[((u32)t1 << 6) + lane]);
        float o2 = b2f(O[((u32)t2 << 6) + lane]), o3 = b2f(O[((u32)t3 << 6) + lane]);
        if (t0 >= NU + NI) omax = fmaxf(omax, o0); else if (t0 >= NU) omin = fminf(omin, o0);
        if (t1 >= NU + NI) omax = fmaxf(omax, o1); else if (t1 >= NU) omin = fminf(omin, o1);
        if (t2 >= NU + NI) omax = fmaxf(omax, o2); else if (t2 >= NU) omin = fminf(omin, o2);
        if (t3 >= NU + NI) omax = fmaxf(omax, o3); else if (t3 >= NU) omin = fminf(omin, o3);
      }
      for (; j < cn; ++j) {
        int t = __shfl(tl, j);
        float o = b2f(O[((u32)t << 6) + lane]);
        if (t >= NU + NI) omax = fmaxf(omax, o); else if (t >= NU) omin = fminf(omin, o);
      }
      float iu = (omin > 1e37f) ? 0.f : omin;
      float ut = (omax < -1e37f) ? 0.f : omax;
      offv = fmaxf(fminf(iu, ut), 0.f);
    } else if (n < NU + NI) {
      float m0 = -3.4e38f, m1 = -3.4e38f, m2 = -3.4e38f, m3 = -3.4e38f;
      int j = 0;
      for (; j + 3 < cn; j += 4) {
        int t0 = __shfl(tl, j),     t1 = __shfl(tl, j + 1);
        int t2 = __shfl(tl, j + 2), t3 = __shfl(tl, j + 3);
        m0 = fmaxf(m0, b2f(O[((u32)t0 << 6) + lane]));
        m1 = fmaxf(m1, b2f(O[((u32)t1 << 6) + lane]));
        m2 = fmaxf(m2, b2f(O[((u32)t2 << 6) + lane]));
        m3 = fmaxf(m3, b2f(O[((u32)t3 << 6) + lane]));
      }
      for (; j < cn; ++j) {
        int t = __shfl(tl, j);
        m0 = fmaxf(m0, b2f(O[((u32)t << 6) + lane]));
      }
      float omax = fmaxf(fmaxf(m0, m1), fmaxf(m2, m3));
      offv = fmaxf((omax < -1e37f) ? 0.f : omax, 0.f);
    } else {
      float m0 = 3.4e38f, m1 = 3.4e38f, m2 = 3.4e38f, m3 = 3.4e38f;
      int j = 0;
      for (; j + 3 < cn; j += 4) {
        int t0 = __shfl(tl, j),     t1 = __shfl(tl, j + 1);
        int t2 = __shfl(tl, j + 2), t3 = __shfl(tl, j + 3);
        m0 = fminf(m0, b2f(O[((u32)t0 << 6) + lane]));
        m1 = fminf(m1, b2f(O[((u32)t1 << 6) + lane]));
        m2 = fminf(m2, b2f(O[((u32)t2 << 6) + lane]));
        m3 = fminf(m3, b2f(O[((u32)t3 << 6) + lane]));
      }
      for (; j < cn; ++j) {
        int t = __shfl(tl, j);
        m0 = fminf(m0, b2f(O[((u32)t << 6) + lane]));
      }
      float omin = fminf(fminf(m0, m1), fminf(m2, m3));
      offv = fmaxf((omin > 1e37f) ? 0.f : omin, 0.f);
    }
    if (FINAL) {
      float* oo;
      if (n < NU)           oo = out + (size_t)NU * D + (size_t)n * D;
      else if (n < NU + NI) oo = out + (size_t)2 * NU * D + (size_t)NI * D + (size_t)(n - NU) * D;
      else                  oo = out + (size_t)(2 * NU + 2 * NI) * D + (size_t)NT * D + (size_t)(n - NU - NI) * D;
      __builtin_nontemporal_store(offv, &oo[lane]);
    } else {
      Oo[((u32)n << 6) + lane] = f2b(offv);
    }
  }
}

extern "C" void kernel_launch(void* const* d_in, const int* in_sizes, int n_in,
                              void* d_out, int out_size, void* d_ws, size_t ws_size,
                              hipStream_t stream) {
  const float* ue = (const float*)d_in[0];
  const float* uo = (const float*)d_in[1];
  const float* ie = (const float*)d_in[2];
  const float* io = (const float*)d_in[3];
  const float* te = (const float*)d_in[4];
  const float* to = (const float*)d_in[5];
  const float* W1 = (const float*)d_in[6];
  const float* b1 = (const float*)d_in[7];
  const float* W2 = (const float*)d_in[8];
  const float* b2 = (const float*)d_in[9];
  const int* head = (const int*)d_in[10];
  const int* tail = (const int*)d_in[11];
  int E = in_sizes[10];

  const size_t NE = (size_t)NN * 64;
  u32* PE  = (u32*)d_ws;              // NE u32 (shared across hops)
  u16* O1  = (u16*)(PE + NE);         // NE u16
  u16* O2  = O1 + NE;                 // NE u16
  u16* Xc  = O2 + NE;                 // NE u16 (hop-1 output emb)
  u16* W1b = Xc + NE;                 // 4096
  u16* W2b = W1b + 4096;              // 4096
  int* cnt = (int*)(W2b + 4096);      // NN
  u16* csr = (u16*)(cnt + NN);        // NN*CAP u16

  hipMemsetAsync(cnt, 0, NN * sizeof(int), stream);
  int sb = (E + 255) / 256;
  prep_kernel<<<PACKB + WB + sb, 256, 0, stream>>>(
      uo, io, to, W1, W2, O1, W1b, W2b, cnt, csr, head, tail, E);

  int mb = (NN + 63) / 64;            // 704
  int ab = (2 * NN + 3) / 4;          // 22500

  // hop 1
  mlp_kernel<1><<<mb, 256, 0, stream>>>(ue, ie, te, nullptr, W1b, W2b, b1, b2, PE);
  agg_kernel<0><<<ab, 256, 0, stream>>>(cnt, csr, PE, O1, O2, Xc, nullptr);
  // hop 2
  mlp_kernel<0><<<mb, 256, 0, stream>>>(nullptr, nullptr, nullptr, Xc, W1b, W2b, b1, b2, PE);
  agg_kernel<1><<<ab, 256, 0, stream>>>(cnt, csr, PE, O2, nullptr, nullptr, (float*)d_out);
}

// Round 7
// 154.823 us; speedup vs baseline: 1.1729x; 1.1729x over previous
//
#include <hip/hip_runtime.h>
#include <math.h>

#define NU 20000
#define NI 20000
#define NT 5000
#define NN 45000
#define D  64
#define CAP 64
#define MBLK 704   // ceil(NN/64) mlp blocks

typedef unsigned short u16;
typedef unsigned int u32;

typedef __attribute__((ext_vector_type(8))) short bf16x8;
typedef __attribute__((ext_vector_type(4))) float f32x4;

__device__ __forceinline__ float b2f(u16 u) {
  return __uint_as_float(((u32)u) << 16);
}
__device__ __forceinline__ u16 f2b(float f) {
  u32 x = __float_as_uint(f);
  u32 r = (x + 0x7fffu + ((x >> 16) & 1u)) >> 16;
  return (u16)r;
}
__device__ __forceinline__ const float* row3(int n, const float* a, const float* b, const float* c) {
  if (n < NU) return a + (size_t)n * D;
  if (n < NU + NI) return b + (size_t)(n - NU) * D;
  return c + (size_t)(n - NU - NI) * D;
}
__device__ __forceinline__ bf16x8 cvtf8(const float* p) {
  bf16x8 r;
#pragma unroll
  for (int j = 0; j < 8; ++j) r[j] = (short)f2b(p[j]);
  return r;
}

// ---------------- MLP body: PEO[node*64+f] = {p = exp(clamp(mlp(x))), e|o<<16} ----------------
template <int FIRST>
__device__ __forceinline__ void mlp_body(
    int bid,
    const float* __restrict__ ue, const float* __restrict__ ie, const float* __restrict__ te,
    const float* __restrict__ uo, const float* __restrict__ io, const float* __restrict__ to,
    const u16* __restrict__ Xc, const u16* __restrict__ O2,
    const float* __restrict__ W1, const float* __restrict__ b1,
    const float* __restrict__ W2, const float* __restrict__ b2,
    uint2* __restrict__ PEO) {
  __shared__ u16 W1L[64][72];
  __shared__ u16 W2L[64][72];
  __shared__ u16 Hs[64][72];
  int tid = threadIdx.x;
  for (int i = tid; i < 4096; i += 256) {
    W1L[i >> 6][i & 63] = f2b(W1[i]);
    W2L[i >> 6][i & 63] = f2b(W2[i]);
  }
  __syncthreads();
  int w = tid >> 6, l = tid & 63;
  int lr = l & 15, kh = l >> 4;
  int nbase = bid * 64 + w * 16;
  int na = nbase + lr; if (na > NN - 1) na = NN - 1;
  bf16x8 A0, A1;
  if (FIRST) {
    const float* xr = row3(na, ue, ie, te);
    A0 = cvtf8(xr + kh * 8);
    A1 = cvtf8(xr + 32 + kh * 8);
  } else {
    A0 = *(const bf16x8*)(Xc + (size_t)na * 64 + kh * 8);
    A1 = *(const bf16x8*)(Xc + (size_t)na * 64 + 32 + kh * 8);
  }
#pragma unroll
  for (int ft = 0; ft < 4; ++ft) {
    int f = ft * 16 + lr;
    bf16x8 Bl = *(const bf16x8*)&W1L[f][kh * 8];
    bf16x8 Bh = *(const bf16x8*)&W1L[f][32 + kh * 8];
    f32x4 z = {0.f, 0.f, 0.f, 0.f};
    z = __builtin_amdgcn_mfma_f32_16x16x32_bf16(A0, Bl, z, 0, 0, 0);
    z = __builtin_amdgcn_mfma_f32_16x16x32_bf16(A1, Bh, z, 0, 0, 0);
    float bb = b1[f];
#pragma unroll
    for (int r = 0; r < 4; ++r)
      Hs[w * 16 + kh * 4 + r][f] = f2b(fmaxf(z[r] + bb, 0.f));
  }
  __syncthreads();
  bf16x8 A20 = *(const bf16x8*)&Hs[w * 16 + lr][kh * 8];
  bf16x8 A21 = *(const bf16x8*)&Hs[w * 16 + lr][32 + kh * 8];
#pragma unroll
  for (int ft = 0; ft < 4; ++ft) {
    int f = ft * 16 + lr;
    bf16x8 Bl = *(const bf16x8*)&W2L[f][kh * 8];
    bf16x8 Bh = *(const bf16x8*)&W2L[f][32 + kh * 8];
    f32x4 z = {0.f, 0.f, 0.f, 0.f};
    z = __builtin_amdgcn_mfma_f32_16x16x32_bf16(A20, Bl, z, 0, 0, 0);
    z = __builtin_amdgcn_mfma_f32_16x16x32_bf16(A21, Bh, z, 0, 0, 0);
    float bb = b2[f];
#pragma unroll
    for (int r = 0; r < 4; ++r) {
      int node = nbase + kh * 4 + r;
      if (node < NN) {
        float a = z[r] + bb;
        float p = __expf(fminf(fmaxf(a, -60.f), 60.f));
        u32 eo;
        if (FIRST) {
          float ev = row3(node, ue, ie, te)[f];
          float ov = fmaxf(row3(node, uo, io, to)[f], 0.f);
          eo = (u32)f2b(ev) | ((u32)f2b(ov) << 16);
        } else {
          u32 idx = ((u32)node << 6) + f;
          eo = (u32)Xc[idx] | ((u32)O2[idx] << 16);
        }
        uint2 v; v.x = __float_as_uint(p); v.y = eo;
        PEO[((size_t)node << 6) + f] = v;
      }
    }
  }
}

// ---------------- fused1: mlp hop-1 + CSR scatter ----------------
__global__ __launch_bounds__(256) void fused1_kernel(
    const float* __restrict__ ue, const float* __restrict__ ie, const float* __restrict__ te,
    const float* __restrict__ uo, const float* __restrict__ io, const float* __restrict__ to,
    const float* __restrict__ W1, const float* __restrict__ b1,
    const float* __restrict__ W2, const float* __restrict__ b2,
    const int* __restrict__ head, const int* __restrict__ tail, int E,
    uint2* __restrict__ PEO, int* __restrict__ cnt, u16* __restrict__ csr) {
  int bid = blockIdx.x;
  if (bid >= MBLK) {
    int i = (bid - MBLK) * 256 + threadIdx.x;
    if (i < E) {
      int h = head[i];
      int s = atomicAdd(&cnt[h], 1);
      if (s < CAP) __builtin_nontemporal_store((u16)tail[i], &csr[h * CAP + s]);
    }
    return;
  }
  mlp_body<1>(bid, ue, ie, te, uo, io, to, nullptr, nullptr, W1, b1, W2, b2, PEO);
}

__global__ __launch_bounds__(256) void mlp2_kernel(
    const u16* __restrict__ Xc, const u16* __restrict__ O2,
    const float* __restrict__ W1, const float* __restrict__ b1,
    const float* __restrict__ W2, const float* __restrict__ b2,
    uint2* __restrict__ PEO) {
  mlp_body<0>(blockIdx.x, nullptr, nullptr, nullptr, nullptr, nullptr, nullptr,
              Xc, O2, W1, b1, W2, b2, PEO);
}

// ---------------- aggregation: one wave per node, merged roles, 8-deep ILP ----------------
template <int FINAL>
__global__ __launch_bounds__(256) void agg_kernel(
    const int* __restrict__ cnt, const u16* __restrict__ csr,
    const uint2* __restrict__ PEO,
    u16* __restrict__ Xco, u16* __restrict__ Oo, float* __restrict__ out) {
  int n = (blockIdx.x * blockDim.x + threadIdx.x) >> 6;
  int lane = threadIdx.x & 63;
  if (n >= NN) return;
  int cn = min(cnt[n], CAP);
  int tl = (lane < cn) ? (int)csr[n * CAP + lane] : 0;
  const char* Pb = (const char*)PEO;
  size_t lo = (size_t)(lane << 3);
  float ss0 = 0.f, ss1 = 0.f, ss2 = 0.f, ss3 = 0.f;
  float ts0 = 0.f, ts1 = 0.f, ts2 = 0.f, ts3 = 0.f;
  float mn0 = 3.4e38f, mn1 = 3.4e38f;
  float mx0 = -3.4e38f, mx1 = -3.4e38f;

#define LD(T) (*(const uint2*)(Pb + ((size_t)(u32)(T) << 9) + lo))
#define ACC(V, SS, TS)                                  \
  { float p_ = __uint_as_float((V).x);                  \
    float e_ = b2f((u16)((V).y & 0xffffu));             \
    SS += p_; TS = fmaf(p_, e_, TS); }
#define OV(V) b2f((u16)((V).y >> 16))

  if (n < NU) {
    int j = 0;
    for (; j + 7 < cn; j += 8) {
      int t0 = __shfl(tl, j),     t1 = __shfl(tl, j + 1);
      int t2 = __shfl(tl, j + 2), t3 = __shfl(tl, j + 3);
      int t4 = __shfl(tl, j + 4), t5 = __shfl(tl, j + 5);
      int t6 = __shfl(tl, j + 6), t7 = __shfl(tl, j + 7);
      uint2 v0 = LD(t0), v1 = LD(t1), v2 = LD(t2), v3 = LD(t3);
      uint2 v4 = LD(t4), v5 = LD(t5), v6 = LD(t6), v7 = LD(t7);
      ACC(v0, ss0, ts0) ACC(v1, ss1, ts1) ACC(v2, ss2, ts2) ACC(v3, ss3, ts3)
      ACC(v4, ss0, ts0) ACC(v5, ss1, ts1) ACC(v6, ss2, ts2) ACC(v7, ss3, ts3)
      if (t0 >= NU + NI) mx0 = fmaxf(mx0, OV(v0)); else if (t0 >= NU) mn0 = fminf(mn0, OV(v0));
      if (t1 >= NU + NI) mx1 = fmaxf(mx1, OV(v1)); else if (t1 >= NU) mn1 = fminf(mn1, OV(v1));
      if (t2 >= NU + NI) mx0 = fmaxf(mx0, OV(v2)); else if (t2 >= NU) mn0 = fminf(mn0, OV(v2));
      if (t3 >= NU + NI) mx1 = fmaxf(mx1, OV(v3)); else if (t3 >= NU) mn1 = fminf(mn1, OV(v3));
      if (t4 >= NU + NI) mx0 = fmaxf(mx0, OV(v4)); else if (t4 >= NU) mn0 = fminf(mn0, OV(v4));
      if (t5 >= NU + NI) mx1 = fmaxf(mx1, OV(v5)); else if (t5 >= NU) mn1 = fminf(mn1, OV(v5));
      if (t6 >= NU + NI) mx0 = fmaxf(mx0, OV(v6)); else if (t6 >= NU) mn0 = fminf(mn0, OV(v6));
      if (t7 >= NU + NI) mx1 = fmaxf(mx1, OV(v7)); else if (t7 >= NU) mn1 = fminf(mn1, OV(v7));
    }
    for (; j < cn; ++j) {
      int t = __shfl(tl, j);
      uint2 v = LD(t);
      ACC(v, ss0, ts0)
      if (t >= NU + NI) mx0 = fmaxf(mx0, OV(v)); else if (t >= NU) mn0 = fminf(mn0, OV(v));
    }
  } else if (n < NU + NI) {
    int j = 0;
    for (; j + 7 < cn; j += 8) {
      int t0 = __shfl(tl, j),     t1 = __shfl(tl, j + 1);
      int t2 = __shfl(tl, j + 2), t3 = __shfl(tl, j + 3);
      int t4 = __shfl(tl, j + 4), t5 = __shfl(tl, j + 5);
      int t6 = __shfl(tl, j + 6), t7 = __shfl(tl, j + 7);
      uint2 v0 = LD(t0), v1 = LD(t1), v2 = LD(t2), v3 = LD(t3);
      uint2 v4 = LD(t4), v5 = LD(t5), v6 = LD(t6), v7 = LD(t7);
      ACC(v0, ss0, ts0) ACC(v1, ss1, ts1) ACC(v2, ss2, ts2) ACC(v3, ss3, ts3)
      ACC(v4, ss0, ts0) ACC(v5, ss1, ts1) ACC(v6, ss2, ts2) ACC(v7, ss3, ts3)
      mx0 = fmaxf(mx0, OV(v0)); mx1 = fmaxf(mx1, OV(v1));
      mx0 = fmaxf(mx0, OV(v2)); mx1 = fmaxf(mx1, OV(v3));
      mx0 = fmaxf(mx0, OV(v4)); mx1 = fmaxf(mx1, OV(v5));
      mx0 = fmaxf(mx0, OV(v6)); mx1 = fmaxf(mx1, OV(v7));
    }
    for (; j < cn; ++j) {
      int t = __shfl(tl, j);
      uint2 v = LD(t);
      ACC(v, ss0, ts0)
      mx0 = fmaxf(mx0, OV(v));
    }
  } else {
    int j = 0;
    for (; j + 7 < cn; j += 8) {
      int t0 = __shfl(tl, j),     t1 = __shfl(tl, j + 1);
      int t2 = __shfl(tl, j + 2), t3 = __shfl(tl, j + 3);
      int t4 = __shfl(tl, j + 4), t5 = __shfl(tl, j + 5);
      int t6 = __shfl(tl, j + 6), t7 = __shfl(tl, j + 7);
      uint2 v0 = LD(t0), v1 = LD(t1), v2 = LD(t2), v3 = LD(t3);
      uint2 v4 = LD(t4), v5 = LD(t5), v6 = LD(t6), v7 = LD(t7);
      ACC(v0, ss0, ts0) ACC(v1, ss1, ts1) ACC(v2, ss2, ts2) ACC(v3, ss3, ts3)
      ACC(v4, ss0, ts0) ACC(v5, ss1, ts1) ACC(v6, ss2, ts2) ACC(v7, ss3, ts3)
      mn0 = fminf(mn0, OV(v0)); mn1 = fminf(mn1, OV(v1));
      mn0 = fminf(mn0, OV(v2)); mn1 = fminf(mn1, OV(v3));
      mn0 = fminf(mn0, OV(v4)); mn1 = fminf(mn1, OV(v5));
      mn0 = fminf(mn0, OV(v6)); mn1 = fminf(mn1, OV(v7));
    }
    for (; j < cn; ++j) {
      int t = __shfl(tl, j);
      uint2 v = LD(t);
      ACC(v, ss0, ts0)
      mn0 = fminf(mn0, OV(v));
    }
  }
#undef LD
#undef ACC
#undef OV

  float ssum = (ss0 + ss1) + (ss2 + ss3);
  float tsum = (ts0 + ts1) + (ts2 + ts3);
  float omin = fminf(mn0, mn1), omax = fmaxf(mx0, mx1);
  float agg = tsum / ssum;
  float sq = agg * agg;
#pragma unroll
  for (int msk = 1; msk < 64; msk <<= 1) sq += __shfl_xor(sq, msk);
  float outv = agg / fmaxf(sqrtf(sq), 1e-12f);
  float offv;
  if (n < NU) {
    float iu = (omin > 1e37f) ? 0.f : omin;
    float ut = (omax < -1e37f) ? 0.f : omax;
    offv = fmaxf(fminf(iu, ut), 0.f);
  } else if (n < NU + NI) {
    offv = fmaxf((omax < -1e37f) ? 0.f : omax, 0.f);
  } else {
    offv = fmaxf((omin > 1e37f) ? 0.f : omin, 0.f);
  }
  if (FINAL) {
    float* oe; float* oo;
    if (n < NU)           { oe = out + (size_t)n * D;
                            oo = out + (size_t)NU * D + (size_t)n * D; }
    else if (n < NU + NI) { int q = n - NU;
                            oe = out + (size_t)2 * NU * D + (size_t)q * D;
                            oo = oe + (size_t)NI * D; }
    else                  { int q = n - NU - NI;
                            oe = out + (size_t)(2 * NU + 2 * NI) * D + (size_t)q * D;
                            oo = oe + (size_t)NT * D; }
    __builtin_nontemporal_store(outv, &oe[lane]);
    __builtin_nontemporal_store(offv, &oo[lane]);
  } else {
    u32 idx = ((u32)n << 6) + lane;
    Xco[idx] = f2b(outv);
    Oo[idx] = f2b(offv);
  }
}

extern "C" void kernel_launch(void* const* d_in, const int* in_sizes, int n_in,
                              void* d_out, int out_size, void* d_ws, size_t ws_size,
                              hipStream_t stream) {
  const float* ue = (const float*)d_in[0];
  const float* uo = (const float*)d_in[1];
  const float* ie = (const float*)d_in[2];
  const float* io = (const float*)d_in[3];
  const float* te = (const float*)d_in[4];
  const float* to = (const float*)d_in[5];
  const float* W1 = (const float*)d_in[6];
  const float* b1 = (const float*)d_in[7];
  const float* W2 = (const float*)d_in[8];
  const float* b2 = (const float*)d_in[9];
  const int* head = (const int*)d_in[10];
  const int* tail = (const int*)d_in[11];
  int E = in_sizes[10];

  const size_t NE = (size_t)NN * 64;
  uint2* PEO = (uint2*)d_ws;            // NE uint2 (23 MB, reused across hops)
  u16* Xc  = (u16*)(PEO + NE);          // NE u16
  u16* O2  = Xc + NE;                   // NE u16
  int* cnt = (int*)(O2 + NE);           // NN
  u16* csr = (u16*)(cnt + NN);          // NN*CAP u16

  hipMemsetAsync(cnt, 0, NN * sizeof(int), stream);
  int sb = (E + 255) / 256;

  // hop 1: fused {W-convert + MLP + PEO pack} || CSR scatter
  fused1_kernel<<<MBLK + sb, 256, 0, stream>>>(
      ue, ie, te, uo, io, to, W1, b1, W2, b2, head, tail, E, PEO, cnt, csr);
  int ab = (NN + 3) / 4;
  agg_kernel<0><<<ab, 256, 0, stream>>>(cnt, csr, PEO, Xc, O2, nullptr);

  // hop 2
  mlp2_kernel<<<MBLK, 256, 0, stream>>>(Xc, O2, W1, b1, W2, b2, PEO);
  agg_kernel<1><<<ab, 256, 0, stream>>>(cnt, csr, PEO, nullptr, nullptr, (float*)d_out);
}

// Round 8
// 150.788 us; speedup vs baseline: 1.2043x; 1.0268x over previous
//
#include <hip/hip_runtime.h>
#include <math.h>

#define NU 20000
#define NI 20000
#define NT 5000
#define NN 45000
#define D  64
#define CAP 64
#define MBLK 704      // ceil(NN/64) mlp blocks (divisible by 8)
#define NXCD 8
#define HRANGE 5625   // NN/NXCD
#define ECHUNK 2048   // edges per scatter block

typedef unsigned short u16;
typedef unsigned int u32;

typedef __attribute__((ext_vector_type(8))) short bf16x8;
typedef __attribute__((ext_vector_type(4))) float f32x4;

__device__ __forceinline__ float b2f(u16 u) {
  return __uint_as_float(((u32)u) << 16);
}
__device__ __forceinline__ u16 f2b(float f) {
  u32 x = __float_as_uint(f);
  u32 r = (x + 0x7fffu + ((x >> 16) & 1u)) >> 16;
  return (u16)r;
}
__device__ __forceinline__ const float* row3(int n, const float* a, const float* b, const float* c) {
  if (n < NU) return a + (size_t)n * D;
  if (n < NU + NI) return b + (size_t)(n - NU) * D;
  return c + (size_t)(n - NU - NI) * D;
}
__device__ __forceinline__ bf16x8 cvtf8(const float* p) {
  bf16x8 r;
#pragma unroll
  for (int j = 0; j < 8; ++j) r[j] = (short)f2b(p[j]);
  return r;
}

// ---------------- MLP body: PEO[node*64+f] = {p = exp(clamp(mlp(x))), e|o<<16} ----------------
template <int FIRST>
__device__ __forceinline__ void mlp_body(
    int bid,
    const float* __restrict__ ue, const float* __restrict__ ie, const float* __restrict__ te,
    const float* __restrict__ uo, const float* __restrict__ io, const float* __restrict__ to,
    const u16* __restrict__ Xc, const u16* __restrict__ O2,
    const float* __restrict__ W1, const float* __restrict__ b1,
    const float* __restrict__ W2, const float* __restrict__ b2,
    uint2* __restrict__ PEO) {
  __shared__ u16 W1L[64][72];
  __shared__ u16 W2L[64][72];
  __shared__ u16 Hs[64][72];
  int tid = threadIdx.x;
  for (int i = tid; i < 4096; i += 256) {
    W1L[i >> 6][i & 63] = f2b(W1[i]);
    W2L[i >> 6][i & 63] = f2b(W2[i]);
  }
  __syncthreads();
  int w = tid >> 6, l = tid & 63;
  int lr = l & 15, kh = l >> 4;
  int nbase = bid * 64 + w * 16;
  int na = nbase + lr; if (na > NN - 1) na = NN - 1;
  bf16x8 A0, A1;
  if (FIRST) {
    const float* xr = row3(na, ue, ie, te);
    A0 = cvtf8(xr + kh * 8);
    A1 = cvtf8(xr + 32 + kh * 8);
  } else {
    A0 = *(const bf16x8*)(Xc + (size_t)na * 64 + kh * 8);
    A1 = *(const bf16x8*)(Xc + (size_t)na * 64 + 32 + kh * 8);
  }
#pragma unroll
  for (int ft = 0; ft < 4; ++ft) {
    int f = ft * 16 + lr;
    bf16x8 Bl = *(const bf16x8*)&W1L[f][kh * 8];
    bf16x8 Bh = *(const bf16x8*)&W1L[f][32 + kh * 8];
    f32x4 z = {0.f, 0.f, 0.f, 0.f};
    z = __builtin_amdgcn_mfma_f32_16x16x32_bf16(A0, Bl, z, 0, 0, 0);
    z = __builtin_amdgcn_mfma_f32_16x16x32_bf16(A1, Bh, z, 0, 0, 0);
    float bb = b1[f];
#pragma unroll
    for (int r = 0; r < 4; ++r)
      Hs[w * 16 + kh * 4 + r][f] = f2b(fmaxf(z[r] + bb, 0.f));
  }
  __syncthreads();
  bf16x8 A20 = *(const bf16x8*)&Hs[w * 16 + lr][kh * 8];
  bf16x8 A21 = *(const bf16x8*)&Hs[w * 16 + lr][32 + kh * 8];
#pragma unroll
  for (int ft = 0; ft < 4; ++ft) {
    int f = ft * 16 + lr;
    bf16x8 Bl = *(const bf16x8*)&W2L[f][kh * 8];
    bf16x8 Bh = *(const bf16x8*)&W2L[f][32 + kh * 8];
    f32x4 z = {0.f, 0.f, 0.f, 0.f};
    z = __builtin_amdgcn_mfma_f32_16x16x32_bf16(A20, Bl, z, 0, 0, 0);
    z = __builtin_amdgcn_mfma_f32_16x16x32_bf16(A21, Bh, z, 0, 0, 0);
    float bb = b2[f];
#pragma unroll
    for (int r = 0; r < 4; ++r) {
      int node = nbase + kh * 4 + r;
      if (node < NN) {
        float a = z[r] + bb;
        float p = __expf(fminf(fmaxf(a, -60.f), 60.f));
        u32 eo;
        if (FIRST) {
          float ev = row3(node, ue, ie, te)[f];
          float ov = fmaxf(row3(node, uo, io, to)[f], 0.f);
          eo = (u32)f2b(ev) | ((u32)f2b(ov) << 16);
        } else {
          u32 idx = ((u32)node << 6) + f;
          eo = (u32)Xc[idx] | ((u32)O2[idx] << 16);
        }
        uint2 v; v.x = __float_as_uint(p); v.y = eo;
        PEO[((size_t)node << 6) + f] = v;
      }
    }
  }
}

// ---------------- fused1: mlp hop-1 + XCD-partitioned CSR scatter ----------------
__global__ __launch_bounds__(256) void fused1_kernel(
    const float* __restrict__ ue, const float* __restrict__ ie, const float* __restrict__ te,
    const float* __restrict__ uo, const float* __restrict__ io, const float* __restrict__ to,
    const float* __restrict__ W1, const float* __restrict__ b1,
    const float* __restrict__ W2, const float* __restrict__ b2,
    const int* __restrict__ head, const int* __restrict__ tail, int E,
    uint2* __restrict__ PEO, int* __restrict__ cnt, u16* __restrict__ csr) {
  int bid = blockIdx.x;
  if (bid >= MBLK) {
    // Scatter blocks: (bid-MBLK)&7 selects a head-range partition; blocks with the
    // same parity land on the same XCD (round-robin dispatch) so each cnt/csr cache
    // line is written by exactly one XCD's L2 -> no cross-XCD partial-line sharing.
    int sbid = bid - MBLK;
    int part = sbid & (NXCD - 1);
    int chunk = sbid >> 3;
    int lo = part * HRANGE, hi = lo + HRANGE;
    int base = chunk * ECHUNK + threadIdx.x;
#pragma unroll
    for (int k = 0; k < ECHUNK / 256; ++k) {
      int i = base + k * 256;
      if (i < E) {
        int h = head[i];
        if (h >= lo && h < hi) {
          int s = atomicAdd(&cnt[h], 1);
          if (s < CAP) csr[h * CAP + s] = (u16)tail[i];
        }
      }
    }
    return;
  }
  mlp_body<1>(bid, ue, ie, te, uo, io, to, nullptr, nullptr, W1, b1, W2, b2, PEO);
}

__global__ __launch_bounds__(256) void mlp2_kernel(
    const u16* __restrict__ Xc, const u16* __restrict__ O2,
    const float* __restrict__ W1, const float* __restrict__ b1,
    const float* __restrict__ W2, const float* __restrict__ b2,
    uint2* __restrict__ PEO) {
  mlp_body<0>(blockIdx.x, nullptr, nullptr, nullptr, nullptr, nullptr, nullptr,
              Xc, O2, W1, b1, W2, b2, PEO);
}

// ---------------- aggregation: one wave per node, merged roles, 8-deep ILP ----------------
template <int FINAL>
__global__ __launch_bounds__(256) void agg_kernel(
    const int* __restrict__ cnt, const u16* __restrict__ csr,
    const uint2* __restrict__ PEO,
    u16* __restrict__ Xco, u16* __restrict__ Oo, float* __restrict__ out) {
  int n = (blockIdx.x * blockDim.x + threadIdx.x) >> 6;
  int lane = threadIdx.x & 63;
  if (n >= NN) return;
  int cn = min(cnt[n], CAP);
  int tl = (lane < cn) ? (int)csr[n * CAP + lane] : 0;
  const char* Pb = (const char*)PEO;
  size_t lo = (size_t)(lane << 3);
  float ss0 = 0.f, ss1 = 0.f, ss2 = 0.f, ss3 = 0.f;
  float ts0 = 0.f, ts1 = 0.f, ts2 = 0.f, ts3 = 0.f;
  float mn0 = 3.4e38f, mn1 = 3.4e38f;
  float mx0 = -3.4e38f, mx1 = -3.4e38f;

#define LD(T) (*(const uint2*)(Pb + ((size_t)(u32)(T) << 9) + lo))
#define ACC(V, SS, TS)                                  \
  { float p_ = __uint_as_float((V).x);                  \
    float e_ = b2f((u16)((V).y & 0xffffu));             \
    SS += p_; TS = fmaf(p_, e_, TS); }
#define OV(V) b2f((u16)((V).y >> 16))

  if (n < NU) {
    int j = 0;
    for (; j + 7 < cn; j += 8) {
      int t0 = __shfl(tl, j),     t1 = __shfl(tl, j + 1);
      int t2 = __shfl(tl, j + 2), t3 = __shfl(tl, j + 3);
      int t4 = __shfl(tl, j + 4), t5 = __shfl(tl, j + 5);
      int t6 = __shfl(tl, j + 6), t7 = __shfl(tl, j + 7);
      uint2 v0 = LD(t0), v1 = LD(t1), v2 = LD(t2), v3 = LD(t3);
      uint2 v4 = LD(t4), v5 = LD(t5), v6 = LD(t6), v7 = LD(t7);
      ACC(v0, ss0, ts0) ACC(v1, ss1, ts1) ACC(v2, ss2, ts2) ACC(v3, ss3, ts3)
      ACC(v4, ss0, ts0) ACC(v5, ss1, ts1) ACC(v6, ss2, ts2) ACC(v7, ss3, ts3)
      if (t0 >= NU + NI) mx0 = fmaxf(mx0, OV(v0)); else if (t0 >= NU) mn0 = fminf(mn0, OV(v0));
      if (t1 >= NU + NI) mx1 = fmaxf(mx1, OV(v1)); else if (t1 >= NU) mn1 = fminf(mn1, OV(v1));
      if (t2 >= NU + NI) mx0 = fmaxf(mx0, OV(v2)); else if (t2 >= NU) mn0 = fminf(mn0, OV(v2));
      if (t3 >= NU + NI) mx1 = fmaxf(mx1, OV(v3)); else if (t3 >= NU) mn1 = fminf(mn1, OV(v3));
      if (t4 >= NU + NI) mx0 = fmaxf(mx0, OV(v4)); else if (t4 >= NU) mn0 = fminf(mn0, OV(v4));
      if (t5 >= NU + NI) mx1 = fmaxf(mx1, OV(v5)); else if (t5 >= NU) mn1 = fminf(mn1, OV(v5));
      if (t6 >= NU + NI) mx0 = fmaxf(mx0, OV(v6)); else if (t6 >= NU) mn0 = fminf(mn0, OV(v6));
      if (t7 >= NU + NI) mx1 = fmaxf(mx1, OV(v7)); else if (t7 >= NU) mn1 = fminf(mn1, OV(v7));
    }
    for (; j < cn; ++j) {
      int t = __shfl(tl, j);
      uint2 v = LD(t);
      ACC(v, ss0, ts0)
      if (t >= NU + NI) mx0 = fmaxf(mx0, OV(v)); else if (t >= NU) mn0 = fminf(mn0, OV(v));
    }
  } else if (n < NU + NI) {
    int j = 0;
    for (; j + 7 < cn; j += 8) {
      int t0 = __shfl(tl, j),     t1 = __shfl(tl, j + 1);
      int t2 = __shfl(tl, j + 2), t3 = __shfl(tl, j + 3);
      int t4 = __shfl(tl, j + 4), t5 = __shfl(tl, j + 5);
      int t6 = __shfl(tl, j + 6), t7 = __shfl(tl, j + 7);
      uint2 v0 = LD(t0), v1 = LD(t1), v2 = LD(t2), v3 = LD(t3);
      uint2 v4 = LD(t4), v5 = LD(t5), v6 = LD(t6), v7 = LD(t7);
      ACC(v0, ss0, ts0) ACC(v1, ss1, ts1) ACC(v2, ss2, ts2) ACC(v3, ss3, ts3)
      ACC(v4, ss0, ts0) ACC(v5, ss1, ts1) ACC(v6, ss2, ts2) ACC(v7, ss3, ts3)
      mx0 = fmaxf(mx0, OV(v0)); mx1 = fmaxf(mx1, OV(v1));
      mx0 = fmaxf(mx0, OV(v2)); mx1 = fmaxf(mx1, OV(v3));
      mx0 = fmaxf(mx0, OV(v4)); mx1 = fmaxf(mx1, OV(v5));
      mx0 = fmaxf(mx0, OV(v6)); mx1 = fmaxf(mx1, OV(v7));
    }
    for (; j < cn; ++j) {
      int t = __shfl(tl, j);
      uint2 v = LD(t);
      ACC(v, ss0, ts0)
      mx0 = fmaxf(mx0, OV(v));
    }
  } else {
    int j = 0;
    for (; j + 7 < cn; j += 8) {
      int t0 = __shfl(tl, j),     t1 = __shfl(tl, j + 1);
      int t2 = __shfl(tl, j + 2), t3 = __shfl(tl, j + 3);
      int t4 = __shfl(tl, j + 4), t5 = __shfl(tl, j + 5);
      int t6 = __shfl(tl, j + 6), t7 = __shfl(tl, j + 7);
      uint2 v0 = LD(t0), v1 = LD(t1), v2 = LD(t2), v3 = LD(t3);
      uint2 v4 = LD(t4), v5 = LD(t5), v6 = LD(t6), v7 = LD(t7);
      ACC(v0, ss0, ts0) ACC(v1, ss1, ts1) ACC(v2, ss2, ts2) ACC(v3, ss3, ts3)
      ACC(v4, ss0, ts0) ACC(v5, ss1, ts1) ACC(v6, ss2, ts2) ACC(v7, ss3, ts3)
      mn0 = fminf(mn0, OV(v0)); mn1 = fminf(mn1, OV(v1));
      mn0 = fminf(mn0, OV(v2)); mn1 = fminf(mn1, OV(v3));
      mn0 = fminf(mn0, OV(v4)); mn1 = fminf(mn1, OV(v5));
      mn0 = fminf(mn0, OV(v6)); mn1 = fminf(mn1, OV(v7));
    }
    for (; j < cn; ++j) {
      int t = __shfl(tl, j);
      uint2 v = LD(t);
      ACC(v, ss0, ts0)
      mn0 = fminf(mn0, OV(v));
    }
  }
#undef LD
#undef ACC
#undef OV

  float ssum = (ss0 + ss1) + (ss2 + ss3);
  float tsum = (ts0 + ts1) + (ts2 + ts3);
  float omin = fminf(mn0, mn1), omax = fmaxf(mx0, mx1);
  float agg = tsum / ssum;
  float sq = agg * agg;
#pragma unroll
  for (int msk = 1; msk < 64; msk <<= 1) sq += __shfl_xor(sq, msk);
  float outv = agg / fmaxf(sqrtf(sq), 1e-12f);
  float offv;
  if (n < NU) {
    float iu = (omin > 1e37f) ? 0.f : omin;
    float ut = (omax < -1e37f) ? 0.f : omax;
    offv = fmaxf(fminf(iu, ut), 0.f);
  } else if (n < NU + NI) {
    offv = fmaxf((omax < -1e37f) ? 0.f : omax, 0.f);
  } else {
    offv = fmaxf((omin > 1e37f) ? 0.f : omin, 0.f);
  }
  if (FINAL) {
    float* oe; float* oo;
    if (n < NU)           { oe = out + (size_t)n * D;
                            oo = out + (size_t)NU * D + (size_t)n * D; }
    else if (n < NU + NI) { int q = n - NU;
                            oe = out + (size_t)2 * NU * D + (size_t)q * D;
                            oo = oe + (size_t)NI * D; }
    else                  { int q = n - NU - NI;
                            oe = out + (size_t)(2 * NU + 2 * NI) * D + (size_t)q * D;
                            oo = oe + (size_t)NT * D; }
    __builtin_nontemporal_store(outv, &oe[lane]);
    __builtin_nontemporal_store(offv, &oo[lane]);
  } else {
    u32 idx = ((u32)n << 6) + lane;
    Xco[idx] = f2b(outv);
    Oo[idx] = f2b(offv);
  }
}

extern "C" void kernel_launch(void* const* d_in, const int* in_sizes, int n_in,
                              void* d_out, int out_size, void* d_ws, size_t ws_size,
                              hipStream_t stream) {
  const float* ue = (const float*)d_in[0];
  const float* uo = (const float*)d_in[1];
  const float* ie = (const float*)d_in[2];
  const float* io = (const float*)d_in[3];
  const float* te = (const float*)d_in[4];
  const float* to = (const float*)d_in[5];
  const float* W1 = (const float*)d_in[6];
  const float* b1 = (const float*)d_in[7];
  const float* W2 = (const float*)d_in[8];
  const float* b2 = (const float*)d_in[9];
  const int* head = (const int*)d_in[10];
  const int* tail = (const int*)d_in[11];
  int E = in_sizes[10];

  const size_t NE = (size_t)NN * 64;
  uint2* PEO = (uint2*)d_ws;            // NE uint2 (23 MB, reused across hops)
  u16* Xc  = (u16*)(PEO + NE);          // NE u16
  u16* O2  = Xc + NE;                   // NE u16
  int* cnt = (int*)(O2 + NE);           // NN
  u16* csr = (u16*)(cnt + NN);          // NN*CAP u16

  hipMemsetAsync(cnt, 0, NN * sizeof(int), stream);
  int nch = (E + ECHUNK - 1) / ECHUNK;

  // hop 1: fused {W-convert + MLP + PEO pack} || XCD-partitioned CSR scatter
  fused1_kernel<<<MBLK + NXCD * nch, 256, 0, stream>>>(
      ue, ie, te, uo, io, to, W1, b1, W2, b2, head, tail, E, PEO, cnt, csr);
  int ab = (NN + 3) / 4;
  agg_kernel<0><<<ab, 256, 0, stream>>>(cnt, csr, PEO, Xc, O2, nullptr);

  // hop 2
  mlp2_kernel<<<MBLK, 256, 0, stream>>>(Xc, O2, W1, b1, W2, b2, PEO);
  agg_kernel<1><<<ab, 256, 0, stream>>>(cnt, csr, PEO, nullptr, nullptr, (float*)d_out);
}